// Round 8
// baseline (771.880 us; speedup 1.0000x reference)
//
#include <hip/hip_runtime.h>

// ---------------------------------------------------------------------------
// GPRGNN forward. R8 == R6/R7 resubmit (two container-infra failures; source
// audited — no OOB/hang candidates; identical resubmit to preserve
// attribution of the channel-quartered agg experiment):
//  * agg: channel-quartered, phase-ordered gather. Wave = (node, quarter);
//    quarter is the SLOW blockIdx dim so quarter phases run ~sequentially.
//    Active gather working set = 50000 nodes x 32ch x 2B = 3.2MB < 4MB L2
//    per XCD (was 12.8MB -> ~70% L2 miss to L3). Same total bytes
//    (4 x 64B = 256B per edge, each 64B line touched in exactly one phase).
//    Paired halves + x4 unroll keep 8 edges in flight.
//  Everything else (parallel scan, bf16 MFMA GEMMs, CSR) unchanged.
// ---------------------------------------------------------------------------

typedef __attribute__((ext_vector_type(8))) short short8;
typedef __attribute__((ext_vector_type(4))) float f32x4;

__device__ __forceinline__ unsigned short f2bf(float f) {
  union { float f; unsigned u; } c{f};
  unsigned u = c.u;
  return (unsigned short)((u + 0x7fff + ((u >> 16) & 1)) >> 16);  // RNE
}
__device__ __forceinline__ float bf2f(unsigned short v) {
  return __uint_as_float((unsigned)v << 16);
}
__device__ __forceinline__ unsigned pack2bf(float a, float b) {
  return (unsigned)f2bf(a) | ((unsigned)f2bf(b) << 16);
}

// async global->LDS, 16B per lane (lds dest = wave-uniform base + lane*16)
__device__ __forceinline__ void gll16(const void* g, void* l) {
  __builtin_amdgcn_global_load_lds(
      (const __attribute__((address_space(1))) unsigned int*)g,
      (__attribute__((address_space(3))) unsigned int*)l, 16, 0, 0);
}

// ---------------- CSR build ----------------
__global__ void hist_kernel(const int* __restrict__ dst, int* __restrict__ deg, int E) {
  int e = blockIdx.x * blockDim.x + threadIdx.x;
  if (e < E) atomicAdd(&deg[dst[e]], 1);
}

// phase 1: per-block (1024 elems) partial sums
__global__ __launch_bounds__(256) void scan_partial(const int* __restrict__ deg,
                                                    int* __restrict__ bsum, int N) {
  int b = blockIdx.x, t = threadIdx.x;
  int lane = t & 63, wave = t >> 6;
  int i0 = b * 1024 + t * 4;
  int s = 0;
  if (i0 + 3 < N) {
    int4 v = *(const int4*)&deg[i0];
    s = v.x + v.y + v.z + v.w;
  } else {
    for (int k = 0; k < 4; ++k)
      if (i0 + k < N) s += deg[i0 + k];
  }
  for (int d = 32; d; d >>= 1) s += __shfl_down(s, d, 64);
  __shared__ int ws[4];
  if (lane == 0) ws[wave] = s;
  __syncthreads();
  if (t == 0) bsum[b] = ws[0] + ws[1] + ws[2] + ws[3];
}

// phase 2: one wave scans <=64 block partials -> exclusive base per block
__global__ void scan_base(const int* __restrict__ bsum, int* __restrict__ base, int nb) {
  int l = threadIdx.x;  // 64
  int v = (l < nb) ? bsum[l] : 0;
  int incl = v;
  for (int d = 1; d < 64; d <<= 1) {
    int t = __shfl_up(incl, d, 64);
    if (l >= d) incl += t;
  }
  if (l < nb) base[l] = incl - v;
}

// phase 3: in-block scan + base -> rowptr & cursor
__global__ __launch_bounds__(256) void scan_emit(const int* __restrict__ deg,
                                                 const int* __restrict__ base,
                                                 int* __restrict__ rowptr,
                                                 int* __restrict__ cursor, int N, int E) {
  int b = blockIdx.x, t = threadIdx.x;
  int lane = t & 63, wave = t >> 6;
  int i0 = b * 1024 + t * 4;
  int d0 = 0, d1 = 0, d2 = 0, d3 = 0;
  if (i0 + 3 < N) {
    int4 v = *(const int4*)&deg[i0];
    d0 = v.x; d1 = v.y; d2 = v.z; d3 = v.w;
  } else {
    if (i0 < N) d0 = deg[i0];
    if (i0 + 1 < N) d1 = deg[i0 + 1];
    if (i0 + 2 < N) d2 = deg[i0 + 2];
    if (i0 + 3 < N) d3 = deg[i0 + 3];
  }
  int s = d0 + d1 + d2 + d3;
  int incl = s;
  for (int d = 1; d < 64; d <<= 1) {
    int tv = __shfl_up(incl, d, 64);
    if (lane >= d) incl += tv;
  }
  __shared__ int ws[4];
  if (lane == 63) ws[wave] = incl;
  __syncthreads();
  int woff = 0;
  for (int wv = 0; wv < wave; ++wv) woff += ws[wv];
  int off = base[b] + woff + incl - s;
  if (i0 < N)     { rowptr[i0] = off;                cursor[i0] = off; }
  if (i0 + 1 < N) { int o = off + d0;                rowptr[i0+1] = o; cursor[i0+1] = o; }
  if (i0 + 2 < N) { int o = off + d0 + d1;           rowptr[i0+2] = o; cursor[i0+2] = o; }
  if (i0 + 3 < N) { int o = off + d0 + d1 + d2;      rowptr[i0+3] = o; cursor[i0+3] = o; }
  if (b == 0 && t == 0) rowptr[N] = E;
}

__global__ void fill_kernel(const int* __restrict__ src, const int* __restrict__ dst,
                            const float* __restrict__ w, int* __restrict__ cursor,
                            int* __restrict__ esrc, float* __restrict__ ew, int E) {
  int e = blockIdx.x * blockDim.x + threadIdx.x;
  if (e < E) {
    int d = dst[e];
    int p = atomicAdd(&cursor[d], 1);
    esrc[p] = src[e];
    ew[p] = w[e];
  }
}

// ---------------- weight convert + transpose (once per call, tiny) ----------
__global__ void conv_w_kernel(const float* __restrict__ W_in,
                              const float* __restrict__ Wl,
                              unsigned short* __restrict__ WinT,
                              unsigned short* __restrict__ WlT) {
  int o = blockIdx.x * blockDim.x + threadIdx.x;
  if (o < 65536) {
    int n = o >> 9, k = o & 511;
    WinT[o] = f2bf(W_in[k * 128 + n]);
  } else if (o < 131072) {
    int p = o - 65536;
    int layer = p >> 14, n = (p >> 7) & 127, k = p & 127;
    WlT[p] = f2bf(Wl[layer * 16384 + k * 128 + n]);
  }
}

// ---------------- bf16 MFMA GEMM: C[M][128] = A[M][K] @ B[K][128] + bias ----
template <int K, bool CONV, bool INMODE>
__global__ __launch_bounds__(256) void gemm_bf16(
    const void* __restrict__ Ain, const unsigned short* __restrict__ BT,
    const float* __restrict__ bias, unsigned short* __restrict__ Cb,
    float* __restrict__ hidden, const float* __restrict__ temp, int M) {
  __shared__ unsigned short As[128 * 32];
  __shared__ unsigned short Bs[128 * 32];

  const int tid = threadIdx.x;
  const int lane = tid & 63;
  const int wave = tid >> 6;
  const int wm = (wave & 1) * 64;
  const int wn = (wave >> 1) * 64;
  const int blockRow = blockIdx.x * 128;

  f32x4 acc[4][4];
#pragma unroll
  for (int i = 0; i < 4; ++i)
#pragma unroll
    for (int j = 0; j < 4; ++j) acc[i][j] = (f32x4){0.f, 0.f, 0.f, 0.f};

  for (int k0 = 0; k0 < K; k0 += 32) {
    __syncthreads();
    if (CONV) {
      const float* A = (const float*)Ain;
      int row = tid >> 1;
      int kc = (tid & 1) * 16;
      int grow = blockRow + row;
      if (grow >= M) grow = M - 1;
      const float* s = &A[(size_t)grow * K + k0 + kc];
      float4 v0 = *(const float4*)(s);
      float4 v1 = *(const float4*)(s + 4);
      float4 v2 = *(const float4*)(s + 8);
      float4 v3 = *(const float4*)(s + 12);
      uint4 p0, p1;
      p0.x = pack2bf(v0.x, v0.y); p0.y = pack2bf(v0.z, v0.w);
      p0.z = pack2bf(v1.x, v1.y); p0.w = pack2bf(v1.z, v1.w);
      p1.x = pack2bf(v2.x, v2.y); p1.y = pack2bf(v2.z, v2.w);
      p1.z = pack2bf(v3.x, v3.y); p1.w = pack2bf(v3.z, v3.w);
      *(uint4*)&As[row * 32 + kc] = p0;
      *(uint4*)&As[row * 32 + kc + 8] = p1;
    } else {
      const unsigned short* A = (const unsigned short*)Ain;
#pragma unroll
      for (int ch = wave; ch < 8; ch += 4) {
        int row = ch * 16 + (lane >> 2);
        int grow = blockRow + row;
        if (grow >= M) grow = M - 1;
        gll16(&A[(size_t)grow * K + k0 + (lane & 3) * 8], (char*)As + ch * 1024);
      }
    }
#pragma unroll
    for (int ch = wave; ch < 8; ch += 4) {
      int row = ch * 16 + (lane >> 2);
      gll16(&BT[(size_t)row * K + k0 + (lane & 3) * 8], (char*)Bs + ch * 1024);
    }
    __syncthreads();

    short8 af[4], bfr[4];
#pragma unroll
    for (int i = 0; i < 4; ++i)
      af[i] = *(const short8*)&As[(wm + i * 16 + (lane & 15)) * 32 + (lane >> 4) * 8];
#pragma unroll
    for (int j = 0; j < 4; ++j)
      bfr[j] = *(const short8*)&Bs[(wn + j * 16 + (lane & 15)) * 32 + (lane >> 4) * 8];
#pragma unroll
    for (int i = 0; i < 4; ++i)
#pragma unroll
      for (int j = 0; j < 4; ++j)
        acc[i][j] =
            __builtin_amdgcn_mfma_f32_16x16x32_bf16(af[i], bfr[j], acc[i][j], 0, 0, 0);
  }

  float t0 = INMODE ? temp[0] : 0.f;
#pragma unroll
  for (int j = 0; j < 4; ++j) {
    int col = wn + j * 16 + (lane & 15);
    float bj = bias[col];
#pragma unroll
    for (int i = 0; i < 4; ++i) {
#pragma unroll
      for (int r = 0; r < 4; ++r) {
        int row = blockRow + wm + i * 16 + (lane >> 4) * 4 + r;
        if (row < M) {
          float v = acc[i][j][r] + bj;
          Cb[(size_t)row * 128 + col] = f2bf(v);
          if (INMODE) hidden[(size_t)row * 128 + col] = t0 * v;
        }
      }
    }
  }
}

// ---------------- aggregation: channel-quartered, phase-ordered -------------
// Wave = (node, quarter q). q = bid / nodeBlocks (SLOW dim -> phases run
// ~sequentially; active gather footprint 3.2MB fits 4MB per-XCD L2).
// Lanes 0-31 take even edge of pair, 32-63 odd edge; lane sl owns channel
// q*32+sl (2B ushort gather; half-wave = one 64B line per edge). x4 unroll
// keeps 8 edges in flight; __shfl_xor(32) merges halves.
__global__ __launch_bounds__(256) void agg_q(
    const int* __restrict__ rowptr, const int* __restrict__ esrc,
    const float* __restrict__ ew, const unsigned short* __restrict__ mb,
    unsigned short* __restrict__ xnext, float* __restrict__ hidden,
    const float* __restrict__ temp, int tempidx, int N, int write_x,
    int nodeBlocks) {
  const int bid = blockIdx.x;
  const int q = bid / nodeBlocks;          // 0..3, slow dimension
  const int nb = bid - q * nodeBlocks;
  const int wave = threadIdx.x >> 6;
  const int lane = threadIdx.x & 63;
  const int node = nb * 4 + wave;
  if (node >= N) return;
  const int half = lane >> 5;
  const int sl = lane & 31;
  const unsigned short* mq = mb + q * 32 + sl;  // index by s*128

  int beg = rowptr[node];
  int end = rowptr[node + 1];

  float a0 = 0.f, a1 = 0.f, a2 = 0.f, a3 = 0.f;
  int j = beg;
  for (; j + 8 <= end; j += 8) {
    int sA = esrc[j + half];     float wA = ew[j + half];
    int sB = esrc[j + 2 + half]; float wB = ew[j + 2 + half];
    int sC = esrc[j + 4 + half]; float wC = ew[j + 4 + half];
    int sD = esrc[j + 6 + half]; float wD = ew[j + 6 + half];
    float vA = bf2f(mq[(size_t)sA * 128]);
    float vB = bf2f(mq[(size_t)sB * 128]);
    float vC = bf2f(mq[(size_t)sC * 128]);
    float vD = bf2f(mq[(size_t)sD * 128]);
    a0 = fmaf(wA, vA, a0);
    a1 = fmaf(wB, vB, a1);
    a2 = fmaf(wC, vC, a2);
    a3 = fmaf(wD, vD, a3);
  }
  for (; j + 2 <= end; j += 2) {
    int s = esrc[j + half];
    float wt = ew[j + half];
    a0 = fmaf(wt, bf2f(mq[(size_t)s * 128]), a0);
  }
  if (j < end) {  // odd tail: half==1 lanes contribute 0
    int s = esrc[j];
    float wt = half ? 0.f : ew[j];
    a0 = fmaf(wt, bf2f(mq[(size_t)s * 128]), a0);
  }

  float s = (a0 + a1) + (a2 + a3);
  s += __shfl_xor(s, 32, 64);

  if (half == 0) {
    float r = fmaxf(s, 0.f);
    size_t o = (size_t)node * 128 + q * 32 + sl;
    if (write_x) xnext[o] = f2bf(r);
    hidden[o] = fmaf(temp[tempidx], r, hidden[o]);
  }
}

// ---------------- fp32 vector GEMM (output projection only) -----------------
__device__ __forceinline__ void fma4(float4& a, float s, const float4& w) {
  a.x = fmaf(s, w.x, a.x);
  a.y = fmaf(s, w.y, a.y);
  a.z = fmaf(s, w.z, a.z);
  a.w = fmaf(s, w.w, a.w);
}

template <int NCOL>
__global__ __launch_bounds__(256) void gemm_f32(
    const float* __restrict__ A, const float* __restrict__ W,
    const float* __restrict__ bias, float* __restrict__ C, int M, int K) {
  constexpr int KT = 64;
  constexpr int CG = NCOL / 8;
  constexpr int RG = 256 / CG;
  constexpr int MROWS = RG * 4;
  constexpr int ACH = MROWS / 4;
  constexpr int WCH = NCOL / 4;

  __shared__ float xs[MROWS * KT];
  __shared__ float wsh[KT * NCOL];

  const int tid = threadIdx.x;
  const int lane = tid & 63;
  const int wave = tid >> 6;
  const int c = tid % CG;
  const int rg = tid / CG;
  const int blockRow = blockIdx.x * MROWS;

  float4 acc0[4], acc1[4];
#pragma unroll
  for (int r = 0; r < 4; ++r) {
    acc0[r] = make_float4(0.f, 0.f, 0.f, 0.f);
    acc1[r] = make_float4(0.f, 0.f, 0.f, 0.f);
  }

  for (int k0 = 0; k0 < K; k0 += KT) {
    __syncthreads();
    for (int ch = wave; ch < ACH; ch += 4) {
      int b = ch * 1024 + lane * 16;
      int row = b >> 8;
      int kb = b & 255;
      int grow = blockRow + row;
      if (grow >= M) grow = M - 1;
      gll16(&A[(size_t)grow * K + k0 + (kb >> 2)], (char*)xs + (size_t)ch * 1024);
    }
    for (int ch = wave; ch < WCH; ch += 4) {
      int b = ch * 1024 + lane * 16;
      int kr = b / (NCOL * 4);
      int cb = b % (NCOL * 4);
      gll16(&W[(size_t)(k0 + kr) * NCOL + (cb >> 2)], (char*)wsh + (size_t)ch * 1024);
    }
    __syncthreads();

#pragma unroll
    for (int k = 0; k < KT; k += 4) {
      float4 av[4];
#pragma unroll
      for (int r = 0; r < 4; ++r)
        av[r] = *reinterpret_cast<const float4*>(&xs[(rg * 4 + r) * KT + k]);
      float4 w0[4], w1[4];
#pragma unroll
      for (int kk = 0; kk < 4; ++kk) {
        w0[kk] = *reinterpret_cast<const float4*>(&wsh[(k + kk) * NCOL + c * 4]);
        w1[kk] = *reinterpret_cast<const float4*>(&wsh[(k + kk) * NCOL + NCOL / 2 + c * 4]);
      }
#pragma unroll
      for (int r = 0; r < 4; ++r) {
        fma4(acc0[r], av[r].x, w0[0]);
        fma4(acc0[r], av[r].y, w0[1]);
        fma4(acc0[r], av[r].z, w0[2]);
        fma4(acc0[r], av[r].w, w0[3]);
        fma4(acc1[r], av[r].x, w1[0]);
        fma4(acc1[r], av[r].y, w1[1]);
        fma4(acc1[r], av[r].z, w1[2]);
        fma4(acc1[r], av[r].w, w1[3]);
      }
    }
  }

  float4 b0 = *reinterpret_cast<const float4*>(&bias[c * 4]);
  float4 b1 = *reinterpret_cast<const float4*>(&bias[NCOL / 2 + c * 4]);
#pragma unroll
  for (int r = 0; r < 4; ++r) {
    int row = blockRow + rg * 4 + r;
    if (row >= M) continue;
    float4 v0 = acc0[r], v1 = acc1[r];
    v0.x += b0.x; v0.y += b0.y; v0.z += b0.z; v0.w += b0.w;
    v1.x += b1.x; v1.y += b1.y; v1.z += b1.z; v1.w += b1.w;
    *reinterpret_cast<float4*>(&C[(size_t)row * NCOL + c * 4]) = v0;
    *reinterpret_cast<float4*>(&C[(size_t)row * NCOL + NCOL / 2 + c * 4]) = v1;
  }
}

extern "C" void kernel_launch(void* const* d_in, const int* in_sizes, int n_in,
                              void* d_out, int out_size, void* d_ws, size_t ws_size,
                              hipStream_t stream) {
  const float* x     = (const float*)d_in[0];
  const float* w     = (const float*)d_in[1];
  const float* W_in  = (const float*)d_in[2];
  const float* b_in  = (const float*)d_in[3];
  const float* Wl    = (const float*)d_in[4];
  const float* bl    = (const float*)d_in[5];
  const float* temp  = (const float*)d_in[6];
  const float* W_out = (const float*)d_in[7];
  const float* b_out = (const float*)d_in[8];
  const int*   src   = (const int*)d_in[9];
  const int*   dst   = (const int*)d_in[10];

  const int IN = 512, H = 128, L = 4;
  const int N = in_sizes[0] / IN;   // 50000
  const int E = in_sizes[1];        // 800000
  const int NB = (N + 1023) / 1024; // 49 (<=64 by construction for this size)

  char* p = (char*)d_ws;
  auto alloc = [&](size_t bytes) {
    void* r = (void*)p;
    p += (bytes + 255) & ~(size_t)255;
    return r;
  };
  unsigned short* xcur_b = (unsigned short*)alloc((size_t)N * H * 2);
  unsigned short* mbuf_b = (unsigned short*)alloc((size_t)N * H * 2);
  float* hidden          = (float*)alloc((size_t)N * H * sizeof(float));
  unsigned short* WinT   = (unsigned short*)alloc((size_t)H * IN * 2);
  unsigned short* WlT    = (unsigned short*)alloc((size_t)L * H * H * 2);
  int*   deg    = (int*)alloc((size_t)N * sizeof(int));
  int*   rowptr = (int*)alloc((size_t)(N + 1) * sizeof(int));
  int*   cursor = (int*)alloc((size_t)N * sizeof(int));
  int*   esrc   = (int*)alloc((size_t)E * sizeof(int));
  float* ew     = (float*)alloc((size_t)E * sizeof(float));
  int*   bsum   = (int*)alloc(64 * sizeof(int));
  int*   base   = (int*)alloc(64 * sizeof(int));

  // ---- CSR build + weight conversion (once per call) ----
  hipMemsetAsync(deg, 0, (size_t)N * sizeof(int), stream);
  hist_kernel<<<(E + 255) / 256, 256, 0, stream>>>(dst, deg, E);
  scan_partial<<<NB, 256, 0, stream>>>(deg, bsum, N);
  scan_base<<<1, 64, 0, stream>>>(bsum, base, NB);
  scan_emit<<<NB, 256, 0, stream>>>(deg, base, rowptr, cursor, N, E);
  fill_kernel<<<(E + 255) / 256, 256, 0, stream>>>(src, dst, w, cursor, esrc, ew, E);
  conv_w_kernel<<<512, 256, 0, stream>>>(W_in, Wl, WinT, WlT);

  const int gB = (N + 127) / 128;   // 391
  const int nodeBlocks = (N + 3) / 4;  // 12500

  // ---- input projection (fused fp32->bf16 conversion of x) ----
  gemm_bf16<512, true, true><<<gB, 256, 0, stream>>>(x, WinT, b_in, xcur_b, hidden,
                                                     temp, N);

  // ---- 4 GPR layers ----
  for (int i = 0; i < L; ++i) {
    gemm_bf16<128, false, false><<<gB, 256, 0, stream>>>(
        xcur_b, WlT + (size_t)i * H * H, bl + (size_t)i * H, mbuf_b, nullptr, temp, N);
    agg_q<<<4 * nodeBlocks, 256, 0, stream>>>(rowptr, esrc, ew, mbuf_b, xcur_b, hidden,
                                              temp, i + 1, N, (i < L - 1) ? 1 : 0,
                                              nodeBlocks);
  }

  // ---- output projection (fp32 vector) ----
  gemm_f32<64><<<(N + 127) / 128, 256, 0, stream>>>(hidden, W_out, b_out,
                                                    (float*)d_out, N, H);
}

// Round 9
// 506.737 us; speedup vs baseline: 1.5232x; 1.5232x over previous
//
#include <hip/hip_runtime.h>

// ---------------------------------------------------------------------------
// GPRGNN forward. R9 changes vs R8 (quartering REVERTED — measured regression,
// FETCH showed per-XCD L2 duplication defeats footprint shrinking):
//  1. agg_v3: full-row gather, 16-lane groups -> 4 edges per wave-load (1KB),
//     x2 unroll (8 edges in flight). NO hidden RMW (pure gather->relu->xnext).
//  2. hidden eliminated: keep x0..x4 bf16; out = (sum temp_i*x_i)@W_out fused
//     into MFMA out-GEMM A-staging (LDS stride 136 = 2-way banks).
//  3. GEMMs / scan / CSR frozen.
// ---------------------------------------------------------------------------

typedef __attribute__((ext_vector_type(8))) short short8;
typedef __attribute__((ext_vector_type(4))) float f32x4;

__device__ __forceinline__ unsigned short f2bf(float f) {
  union { float f; unsigned u; } c{f};
  unsigned u = c.u;
  return (unsigned short)((u + 0x7fff + ((u >> 16) & 1)) >> 16);  // RNE
}
__device__ __forceinline__ float bf2f_lo(unsigned v) {
  return __uint_as_float(v << 16);
}
__device__ __forceinline__ float bf2f_hi(unsigned v) {
  return __uint_as_float(v & 0xffff0000u);
}
__device__ __forceinline__ unsigned pack2bf(float a, float b) {
  return (unsigned)f2bf(a) | ((unsigned)f2bf(b) << 16);
}

// async global->LDS, 16B per lane (lds dest = wave-uniform base + lane*16)
__device__ __forceinline__ void gll16(const void* g, void* l) {
  __builtin_amdgcn_global_load_lds(
      (const __attribute__((address_space(1))) unsigned int*)g,
      (__attribute__((address_space(3))) unsigned int*)l, 16, 0, 0);
}

// ---------------- CSR build ----------------
__global__ void hist_kernel(const int* __restrict__ dst, int* __restrict__ deg, int E) {
  int e = blockIdx.x * blockDim.x + threadIdx.x;
  if (e < E) atomicAdd(&deg[dst[e]], 1);
}

__global__ __launch_bounds__(256) void scan_partial(const int* __restrict__ deg,
                                                    int* __restrict__ bsum, int N) {
  int b = blockIdx.x, t = threadIdx.x;
  int lane = t & 63, wave = t >> 6;
  int i0 = b * 1024 + t * 4;
  int s = 0;
  if (i0 + 3 < N) {
    int4 v = *(const int4*)&deg[i0];
    s = v.x + v.y + v.z + v.w;
  } else {
    for (int k = 0; k < 4; ++k)
      if (i0 + k < N) s += deg[i0 + k];
  }
  for (int d = 32; d; d >>= 1) s += __shfl_down(s, d, 64);
  __shared__ int ws[4];
  if (lane == 0) ws[wave] = s;
  __syncthreads();
  if (t == 0) bsum[b] = ws[0] + ws[1] + ws[2] + ws[3];
}

__global__ void scan_base(const int* __restrict__ bsum, int* __restrict__ base, int nb) {
  int l = threadIdx.x;  // 64
  int v = (l < nb) ? bsum[l] : 0;
  int incl = v;
  for (int d = 1; d < 64; d <<= 1) {
    int t = __shfl_up(incl, d, 64);
    if (l >= d) incl += t;
  }
  if (l < nb) base[l] = incl - v;
}

__global__ __launch_bounds__(256) void scan_emit(const int* __restrict__ deg,
                                                 const int* __restrict__ base,
                                                 int* __restrict__ rowptr,
                                                 int* __restrict__ cursor, int N, int E) {
  int b = blockIdx.x, t = threadIdx.x;
  int lane = t & 63, wave = t >> 6;
  int i0 = b * 1024 + t * 4;
  int d0 = 0, d1 = 0, d2 = 0, d3 = 0;
  if (i0 + 3 < N) {
    int4 v = *(const int4*)&deg[i0];
    d0 = v.x; d1 = v.y; d2 = v.z; d3 = v.w;
  } else {
    if (i0 < N) d0 = deg[i0];
    if (i0 + 1 < N) d1 = deg[i0 + 1];
    if (i0 + 2 < N) d2 = deg[i0 + 2];
    if (i0 + 3 < N) d3 = deg[i0 + 3];
  }
  int s = d0 + d1 + d2 + d3;
  int incl = s;
  for (int d = 1; d < 64; d <<= 1) {
    int tv = __shfl_up(incl, d, 64);
    if (lane >= d) incl += tv;
  }
  __shared__ int ws[4];
  if (lane == 63) ws[wave] = incl;
  __syncthreads();
  int woff = 0;
  for (int wv = 0; wv < wave; ++wv) woff += ws[wv];
  int off = base[b] + woff + incl - s;
  if (i0 < N)     { rowptr[i0] = off;                cursor[i0] = off; }
  if (i0 + 1 < N) { int o = off + d0;                rowptr[i0+1] = o; cursor[i0+1] = o; }
  if (i0 + 2 < N) { int o = off + d0 + d1;           rowptr[i0+2] = o; cursor[i0+2] = o; }
  if (i0 + 3 < N) { int o = off + d0 + d1 + d2;      rowptr[i0+3] = o; cursor[i0+3] = o; }
  if (b == 0 && t == 0) rowptr[N] = E;
}

__global__ void fill_kernel(const int* __restrict__ src, const int* __restrict__ dst,
                            const float* __restrict__ w, int* __restrict__ cursor,
                            int* __restrict__ esrc, float* __restrict__ ew, int E) {
  int e = blockIdx.x * blockDim.x + threadIdx.x;
  if (e < E) {
    int d = dst[e];
    int p = atomicAdd(&cursor[d], 1);
    esrc[p] = src[e];
    ew[p] = w[e];
  }
}

// ---------------- weight convert + transpose (once per call, tiny) ----------
// WinT[n][k]=bf16(W_in[k][n]); WlT[l][n][k]=bf16(Wl[l][k][n]);
// WoutT[n][k]=bf16(W_out[k][n]) (64 x 128).
__global__ void conv_w_kernel(const float* __restrict__ W_in,
                              const float* __restrict__ Wl,
                              const float* __restrict__ W_out,
                              unsigned short* __restrict__ WinT,
                              unsigned short* __restrict__ WlT,
                              unsigned short* __restrict__ WoutT) {
  int o = blockIdx.x * blockDim.x + threadIdx.x;
  if (o < 65536) {
    int n = o >> 9, k = o & 511;
    WinT[o] = f2bf(W_in[k * 128 + n]);
  } else if (o < 131072) {
    int p = o - 65536;
    int layer = p >> 14, n = (p >> 7) & 127, k = p & 127;
    WlT[p] = f2bf(Wl[layer * 16384 + k * 128 + n]);
  } else if (o < 139264) {
    int p = o - 131072;
    int n = p >> 7, k = p & 127;
    WoutT[p] = f2bf(W_out[k * 64 + n]);
  }
}

// ---------------- bf16 MFMA GEMM: C[M][128] = A[M][K] @ B[K][128] + bias ----
template <int K, bool CONV>
__global__ __launch_bounds__(256) void gemm_bf16(
    const void* __restrict__ Ain, const unsigned short* __restrict__ BT,
    const float* __restrict__ bias, unsigned short* __restrict__ Cb, int M) {
  __shared__ unsigned short As[128 * 32];
  __shared__ unsigned short Bs[128 * 32];

  const int tid = threadIdx.x;
  const int lane = tid & 63;
  const int wave = tid >> 6;
  const int wm = (wave & 1) * 64;
  const int wn = (wave >> 1) * 64;
  const int blockRow = blockIdx.x * 128;

  f32x4 acc[4][4];
#pragma unroll
  for (int i = 0; i < 4; ++i)
#pragma unroll
    for (int j = 0; j < 4; ++j) acc[i][j] = (f32x4){0.f, 0.f, 0.f, 0.f};

  for (int k0 = 0; k0 < K; k0 += 32) {
    __syncthreads();
    if (CONV) {
      const float* A = (const float*)Ain;
      int row = tid >> 1;
      int kc = (tid & 1) * 16;
      int grow = blockRow + row;
      if (grow >= M) grow = M - 1;
      const float* s = &A[(size_t)grow * K + k0 + kc];
      float4 v0 = *(const float4*)(s);
      float4 v1 = *(const float4*)(s + 4);
      float4 v2 = *(const float4*)(s + 8);
      float4 v3 = *(const float4*)(s + 12);
      uint4 p0, p1;
      p0.x = pack2bf(v0.x, v0.y); p0.y = pack2bf(v0.z, v0.w);
      p0.z = pack2bf(v1.x, v1.y); p0.w = pack2bf(v1.z, v1.w);
      p1.x = pack2bf(v2.x, v2.y); p1.y = pack2bf(v2.z, v2.w);
      p1.z = pack2bf(v3.x, v3.y); p1.w = pack2bf(v3.z, v3.w);
      *(uint4*)&As[row * 32 + kc] = p0;
      *(uint4*)&As[row * 32 + kc + 8] = p1;
    } else {
      const unsigned short* A = (const unsigned short*)Ain;
#pragma unroll
      for (int ch = wave; ch < 8; ch += 4) {
        int row = ch * 16 + (lane >> 2);
        int grow = blockRow + row;
        if (grow >= M) grow = M - 1;
        gll16(&A[(size_t)grow * K + k0 + (lane & 3) * 8], (char*)As + ch * 1024);
      }
    }
#pragma unroll
    for (int ch = wave; ch < 8; ch += 4) {
      int row = ch * 16 + (lane >> 2);
      gll16(&BT[(size_t)row * K + k0 + (lane & 3) * 8], (char*)Bs + ch * 1024);
    }
    __syncthreads();

    short8 af[4], bfr[4];
#pragma unroll
    for (int i = 0; i < 4; ++i)
      af[i] = *(const short8*)&As[(wm + i * 16 + (lane & 15)) * 32 + (lane >> 4) * 8];
#pragma unroll
    for (int j = 0; j < 4; ++j)
      bfr[j] = *(const short8*)&Bs[(wn + j * 16 + (lane & 15)) * 32 + (lane >> 4) * 8];
#pragma unroll
    for (int i = 0; i < 4; ++i)
#pragma unroll
      for (int j = 0; j < 4; ++j)
        acc[i][j] =
            __builtin_amdgcn_mfma_f32_16x16x32_bf16(af[i], bfr[j], acc[i][j], 0, 0, 0);
  }

#pragma unroll
  for (int j = 0; j < 4; ++j) {
    int col = wn + j * 16 + (lane & 15);
    float bj = bias[col];
#pragma unroll
    for (int i = 0; i < 4; ++i) {
#pragma unroll
      for (int r = 0; r < 4; ++r) {
        int row = blockRow + wm + i * 16 + (lane >> 4) * 4 + r;
        if (row < M) Cb[(size_t)row * 128 + col] = f2bf(acc[i][j][r] + bj);
      }
    }
  }
}

// ---------------- aggregation v3: 4 edges per wave-load, no hidden ----------
// Lane group g=lane>>4 owns edge slot g of a 4-edge batch; c=lane&15 owns
// channels c*8..c*8+7 (uint4 = 16B; 4 edges x 256B = 1KB per wave-load).
// x2 unroll = 8 edges in flight. shfl_xor(16),(32) sums the 4 slots.
__global__ __launch_bounds__(256) void agg_v3(
    const int* __restrict__ rowptr, const int* __restrict__ esrc,
    const float* __restrict__ ew, const unsigned short* __restrict__ mb,
    unsigned short* __restrict__ xnext, int N) {
  const int node = blockIdx.x * 4 + (threadIdx.x >> 6);
  const int lane = threadIdx.x & 63;
  if (node >= N) return;
  const int g = lane >> 4;
  const int c = lane & 15;
  const int beg = rowptr[node];
  const int end = rowptr[node + 1];
  const unsigned short* mc = mb + c * 8;

  float aA[8] = {0.f, 0.f, 0.f, 0.f, 0.f, 0.f, 0.f, 0.f};
  float aB[8] = {0.f, 0.f, 0.f, 0.f, 0.f, 0.f, 0.f, 0.f};

  int j = beg;
  for (; j + 8 <= end; j += 8) {
    int sA = esrc[j + g];     float wA = ew[j + g];
    int sB = esrc[j + 4 + g]; float wB = ew[j + 4 + g];
    uint4 vA = *(const uint4*)&mc[(size_t)sA * 128];
    uint4 vB = *(const uint4*)&mc[(size_t)sB * 128];
    aA[0] = fmaf(wA, bf2f_lo(vA.x), aA[0]); aA[1] = fmaf(wA, bf2f_hi(vA.x), aA[1]);
    aA[2] = fmaf(wA, bf2f_lo(vA.y), aA[2]); aA[3] = fmaf(wA, bf2f_hi(vA.y), aA[3]);
    aA[4] = fmaf(wA, bf2f_lo(vA.z), aA[4]); aA[5] = fmaf(wA, bf2f_hi(vA.z), aA[5]);
    aA[6] = fmaf(wA, bf2f_lo(vA.w), aA[6]); aA[7] = fmaf(wA, bf2f_hi(vA.w), aA[7]);
    aB[0] = fmaf(wB, bf2f_lo(vB.x), aB[0]); aB[1] = fmaf(wB, bf2f_hi(vB.x), aB[1]);
    aB[2] = fmaf(wB, bf2f_lo(vB.y), aB[2]); aB[3] = fmaf(wB, bf2f_hi(vB.y), aB[3]);
    aB[4] = fmaf(wB, bf2f_lo(vB.z), aB[4]); aB[5] = fmaf(wB, bf2f_hi(vB.z), aB[5]);
    aB[6] = fmaf(wB, bf2f_lo(vB.w), aB[6]); aB[7] = fmaf(wB, bf2f_hi(vB.w), aB[7]);
  }
  if (j + 4 <= end) {
    int s = esrc[j + g]; float wt = ew[j + g];
    uint4 v = *(const uint4*)&mc[(size_t)s * 128];
    aA[0] = fmaf(wt, bf2f_lo(v.x), aA[0]); aA[1] = fmaf(wt, bf2f_hi(v.x), aA[1]);
    aA[2] = fmaf(wt, bf2f_lo(v.y), aA[2]); aA[3] = fmaf(wt, bf2f_hi(v.y), aA[3]);
    aA[4] = fmaf(wt, bf2f_lo(v.z), aA[4]); aA[5] = fmaf(wt, bf2f_hi(v.z), aA[5]);
    aA[6] = fmaf(wt, bf2f_lo(v.w), aA[6]); aA[7] = fmaf(wt, bf2f_hi(v.w), aA[7]);
    j += 4;
  }
  if (j < end) {  // 1..3 remaining edges; slots past end contribute 0
    int idx = j + g;
    int s = esrc[(idx < end) ? idx : (end - 1)];
    float wt = (idx < end) ? ew[idx] : 0.f;
    uint4 v = *(const uint4*)&mc[(size_t)s * 128];
    aB[0] = fmaf(wt, bf2f_lo(v.x), aB[0]); aB[1] = fmaf(wt, bf2f_hi(v.x), aB[1]);
    aB[2] = fmaf(wt, bf2f_lo(v.y), aB[2]); aB[3] = fmaf(wt, bf2f_hi(v.y), aB[3]);
    aB[4] = fmaf(wt, bf2f_lo(v.z), aB[4]); aB[5] = fmaf(wt, bf2f_hi(v.z), aB[5]);
    aB[6] = fmaf(wt, bf2f_lo(v.w), aB[6]); aB[7] = fmaf(wt, bf2f_hi(v.w), aB[7]);
  }

  float r[8];
#pragma unroll
  for (int k = 0; k < 8; ++k) {
    float s = aA[k] + aB[k];
    s += __shfl_xor(s, 16, 64);
    s += __shfl_xor(s, 32, 64);
    r[k] = fmaxf(s, 0.f);
  }
  if (g == 0) {
    uint4 pk;
    pk.x = pack2bf(r[0], r[1]);
    pk.y = pack2bf(r[2], r[3]);
    pk.z = pack2bf(r[4], r[5]);
    pk.w = pack2bf(r[6], r[7]);
    *(uint4*)&xnext[(size_t)node * 128 + c * 8] = pk;
  }
}

// ---------------- fused output GEMM: out = (sum temp_i*x_i) @ W_out + b ----
// A combined in LDS from 5 bf16 sources (fp32 combine, bf16 round). K=128
// single tile. LDS stride 136 ushorts (272B) -> 2-way banks on b128 reads.
__global__ __launch_bounds__(256) void gemm_out(
    const unsigned short* __restrict__ xb,  // 5 contiguous [N][128] buffers
    const float* __restrict__ temp, const unsigned short* __restrict__ WoT,
    const float* __restrict__ b_out, float* __restrict__ out, int M) {
  __shared__ unsigned short As[128 * 136];  // 34816 B
  __shared__ unsigned short Bs[64 * 136];   // 17408 B

  const int tid = threadIdx.x;
  const int lane = tid & 63;
  const int wave = tid >> 6;
  const int blockRow = blockIdx.x * 128;

  float t[5];
#pragma unroll
  for (int i = 0; i < 5; ++i) t[i] = temp[i];

  // stage A: thread = (row = tid/2, 64-ch half); combine 5 sources in fp32
  {
    int row = tid >> 1;
    int grow = blockRow + row;
    if (grow >= M) grow = M - 1;
    int ch0 = (tid & 1) * 64;
#pragma unroll
    for (int gch = 0; gch < 64; gch += 8) {
      float acc[8] = {0.f, 0.f, 0.f, 0.f, 0.f, 0.f, 0.f, 0.f};
#pragma unroll
      for (int i = 0; i < 5; ++i) {
        uint4 v = *(const uint4*)&xb[((size_t)i * M + grow) * 128 + ch0 + gch];
        acc[0] = fmaf(t[i], bf2f_lo(v.x), acc[0]);
        acc[1] = fmaf(t[i], bf2f_hi(v.x), acc[1]);
        acc[2] = fmaf(t[i], bf2f_lo(v.y), acc[2]);
        acc[3] = fmaf(t[i], bf2f_hi(v.y), acc[3]);
        acc[4] = fmaf(t[i], bf2f_lo(v.z), acc[4]);
        acc[5] = fmaf(t[i], bf2f_hi(v.z), acc[5]);
        acc[6] = fmaf(t[i], bf2f_lo(v.w), acc[6]);
        acc[7] = fmaf(t[i], bf2f_hi(v.w), acc[7]);
      }
      uint4 pk;
      pk.x = pack2bf(acc[0], acc[1]);
      pk.y = pack2bf(acc[2], acc[3]);
      pk.z = pack2bf(acc[4], acc[5]);
      pk.w = pack2bf(acc[6], acc[7]);
      *(uint4*)&As[row * 136 + ch0 + gch] = pk;
    }
  }
  // stage B: WoT[64][128] -> Bs[64][136]
  for (int i = tid; i < 64 * 16; i += 256) {
    int row = i >> 4;
    int chunk = (i & 15) * 8;
    *(uint4*)&Bs[row * 136 + chunk] = *(const uint4*)&WoT[row * 128 + chunk];
  }
  __syncthreads();

  // MFMA: wave owns rows [wave*32, wave*32+32); 4 col-frags; K=128 (4 kfrags)
  f32x4 acc[2][4];
#pragma unroll
  for (int i = 0; i < 2; ++i)
#pragma unroll
    for (int j = 0; j < 4; ++j) acc[i][j] = (f32x4){0.f, 0.f, 0.f, 0.f};

#pragma unroll
  for (int kf = 0; kf < 4; ++kf) {
    short8 af[2], bfr[4];
#pragma unroll
    for (int i = 0; i < 2; ++i)
      af[i] = *(const short8*)&As[(wave * 32 + i * 16 + (lane & 15)) * 136 + kf * 32 +
                                  (lane >> 4) * 8];
#pragma unroll
    for (int j = 0; j < 4; ++j)
      bfr[j] = *(const short8*)&Bs[(j * 16 + (lane & 15)) * 136 + kf * 32 +
                                   (lane >> 4) * 8];
#pragma unroll
    for (int i = 0; i < 2; ++i)
#pragma unroll
      for (int j = 0; j < 4; ++j)
        acc[i][j] =
            __builtin_amdgcn_mfma_f32_16x16x32_bf16(af[i], bfr[j], acc[i][j], 0, 0, 0);
  }

#pragma unroll
  for (int j = 0; j < 4; ++j) {
    int col = j * 16 + (lane & 15);
    float bj = b_out[col];
#pragma unroll
    for (int i = 0; i < 2; ++i) {
#pragma unroll
      for (int r = 0; r < 4; ++r) {
        int row = blockRow + wave * 32 + i * 16 + (lane >> 4) * 4 + r;
        if (row < M) out[(size_t)row * 64 + col] = acc[i][j][r] + bj;
      }
    }
  }
}

extern "C" void kernel_launch(void* const* d_in, const int* in_sizes, int n_in,
                              void* d_out, int out_size, void* d_ws, size_t ws_size,
                              hipStream_t stream) {
  const float* x     = (const float*)d_in[0];
  const float* w     = (const float*)d_in[1];
  const float* W_in  = (const float*)d_in[2];
  const float* b_in  = (const float*)d_in[3];
  const float* Wl    = (const float*)d_in[4];
  const float* bl    = (const float*)d_in[5];
  const float* temp  = (const float*)d_in[6];
  const float* W_out = (const float*)d_in[7];
  const float* b_out = (const float*)d_in[8];
  const int*   src   = (const int*)d_in[9];
  const int*   dst   = (const int*)d_in[10];

  const int IN = 512, H = 128, L = 4;
  const int N = in_sizes[0] / IN;   // 50000
  const int E = in_sizes[1];        // 800000
  const int NB = (N + 1023) / 1024; // 49 (<=64)
  const size_t NH = (size_t)N * H;

  char* p = (char*)d_ws;
  auto alloc = [&](size_t bytes) {
    void* r = (void*)p;
    p += (bytes + 255) & ~(size_t)255;
    return r;
  };
  unsigned short* xb     = (unsigned short*)alloc(5 * NH * 2);  // x0..x4
  unsigned short* mbuf_b = (unsigned short*)alloc(NH * 2);
  unsigned short* WinT   = (unsigned short*)alloc((size_t)H * IN * 2);
  unsigned short* WlT    = (unsigned short*)alloc((size_t)L * H * H * 2);
  unsigned short* WoutT  = (unsigned short*)alloc((size_t)64 * H * 2);
  int*   deg    = (int*)alloc((size_t)N * sizeof(int));
  int*   rowptr = (int*)alloc((size_t)(N + 1) * sizeof(int));
  int*   cursor = (int*)alloc((size_t)N * sizeof(int));
  int*   esrc   = (int*)alloc((size_t)E * sizeof(int));
  float* ew     = (float*)alloc((size_t)E * sizeof(float));
  int*   bsum   = (int*)alloc(64 * sizeof(int));
  int*   base   = (int*)alloc(64 * sizeof(int));

  // ---- CSR build + weight conversion (once per call) ----
  hipMemsetAsync(deg, 0, (size_t)N * sizeof(int), stream);
  hist_kernel<<<(E + 255) / 256, 256, 0, stream>>>(dst, deg, E);
  scan_partial<<<NB, 256, 0, stream>>>(deg, bsum, N);
  scan_base<<<1, 64, 0, stream>>>(bsum, base, NB);
  scan_emit<<<NB, 256, 0, stream>>>(deg, base, rowptr, cursor, N, E);
  fill_kernel<<<(E + 255) / 256, 256, 0, stream>>>(src, dst, w, cursor, esrc, ew, E);
  conv_w_kernel<<<544, 256, 0, stream>>>(W_in, Wl, W_out, WinT, WlT, WoutT);

  const int gB = (N + 127) / 128;  // 391

  // ---- input projection -> x0 (bf16, pre-relu) ----
  gemm_bf16<512, true><<<gB, 256, 0, stream>>>(x, WinT, b_in, xb, N);

  // ---- 4 GPR layers: x_{i+1} = relu(segsum(w * (x_i@Wl_i+bl_i)[src])) ----
  for (int i = 0; i < L; ++i) {
    gemm_bf16<128, false><<<gB, 256, 0, stream>>>(
        xb + (size_t)i * NH, WlT + (size_t)i * H * H, bl + (size_t)i * H, mbuf_b, N);
    agg_v3<<<(N + 3) / 4, 256, 0, stream>>>(rowptr, esrc, ew, mbuf_b,
                                            xb + (size_t)(i + 1) * NH, N);
  }

  // ---- fused output: out = (sum temp_i * x_i) @ W_out + b_out ----
  gemm_out<<<gB, 256, 0, stream>>>(xb, temp, WoutT, b_out, (float*)d_out, N);
}